// Round 4
// baseline (71.565 us; speedup 1.0000x reference)
//
#include <hip/hip_runtime.h>
#include <math.h>

#define N_MAX 4096
#define TPB   256
#define EPB   16                 // elements ranked per block
#define TPE   16                 // thread-parts per element
#define IT4   (N_MAX / 4 / TPE)  // 64 float4 per part
#define CS    32
#define NCHUNK (N_MAX / CS)      // 128
#define NTHR_M 1024              // mono fallback block size

// Reduce 4 float sums across the block (nthr threads). scr >= 64 floats.
__device__ inline void block_reduce4(float& x, float& y, float& z, float& w,
                                     volatile float* scr, int tid, int nthr) {
#pragma unroll
  for (int o = 32; o > 0; o >>= 1) {
    x += __shfl_down(x, o, 64);
    y += __shfl_down(y, o, 64);
    z += __shfl_down(z, o, 64);
    w += __shfl_down(w, o, 64);
  }
  const int wv = tid >> 6, ln = tid & 63;
  __syncthreads();
  if (ln == 0) { scr[wv] = x; scr[16 + wv] = y; scr[32 + wv] = z; scr[48 + wv] = w; }
  __syncthreads();
  if (tid == 0) {
    float sx = 0.f, sy = 0.f, sz = 0.f, sw = 0.f;
    for (int k = 0; k < nthr / 64; ++k) {
      sx += scr[k]; sy += scr[16 + k]; sz += scr[32 + k]; sw += scr[48 + k];
    }
    scr[0] = sx; scr[16] = sy; scr[32] = sz; scr[48] = sw;
  }
  __syncthreads();
  x = scr[0]; y = scr[16]; z = scr[32]; w = scr[48];
}

// ---- Fused: counting-rank scatter by all blocks; last block runs PAV tail.
__global__ __launch_bounds__(TPB, 1)
void fused_kernel(const float* __restrict__ pred,
                  const float* __restrict__ target,
                  float* __restrict__ out,
                  unsigned* __restrict__ ctr,
                  float* __restrict__ trip,   // nblk x 4 floats
                  float* __restrict__ sv,     // sorted values
                  float* __restrict__ stv,    // target permuted to sorted order
                  int n, int nblk) {
  __shared__ __align__(16) float s_a[N_MAX];   // pred staged; reused as s_val in tail
  __shared__ __align__(16) float s_ts[N_MAX];  // sorted target (tail)
  __shared__ double st_sum[N_MAX];             // PAV stacks (f64 block sums)
  __shared__ int    st_cnt[N_MAX];
  __shared__ int    st_start[N_MAX];
  __shared__ float  s_q[N_MAX];                // per-merged-block mean + C
  __shared__ int    s_nb[NCHUNK];
  __shared__ int    s_scan[NCHUNK];
  __shared__ float  s_red[64];
  __shared__ int    s_w[4][EPB];
  __shared__ float  s_t3[3][EPB];
  __shared__ int    s_last;
  __shared__ int    s_sp;

  const int tid = threadIdx.x;
  const int bid = blockIdx.x;

  // ---- Phase 1 (all blocks): stage pred, counting-rank EPB elements ----
  for (int i = tid; i < N_MAX; i += TPB)
    s_a[i] = (i < n) ? pred[i] : -3.0e38f;
  __syncthreads();

  const int wv = tid >> 6, ln = tid & 63;
  const int el = ln & (EPB - 1), sub = ln >> 4;
  const int part = wv * 4 + sub;            // 0..15
  const int eg = bid * EPB + el;
  int cnt = 0;
  if (eg < n) {
    const float my = s_a[eg];
#pragma unroll 8
    for (int it = 0; it < IT4; ++it) {
      const int j4 = it * TPE + part;
      const float4 v = *(const float4*)&s_a[j4 * 4];
      const int j = j4 * 4;
      cnt += (v.x > my) || (v.x == my && (j    ) < eg);
      cnt += (v.y > my) || (v.y == my && (j + 1) < eg);
      cnt += (v.z > my) || (v.z == my && (j + 2) < eg);
      cnt += (v.w > my) || (v.w == my && (j + 3) < eg);
    }
  }
  cnt += __shfl_down(cnt, 32, 64);
  cnt += __shfl_down(cnt, 16, 64);
  if (ln < EPB) s_w[wv][ln] = cnt;
  __syncthreads();
  if (tid < EPB) {
    const int e2 = bid * EPB + tid;
    if (e2 < n) {
      const float p = s_a[e2];
      const float t = target[e2];
      const int pos = s_w[0][tid] + s_w[1][tid] + s_w[2][tid] + s_w[3][tid];
      sv[pos] = p; stv[pos] = t;
      const float d = p - t;
      s_t3[0][tid] = d * d; s_t3[1][tid] = t; s_t3[2][tid] = t * t;
    } else {
      s_t3[0][tid] = 0.f; s_t3[1][tid] = 0.f; s_t3[2][tid] = 0.f;
    }
  }
  __syncthreads();   // drains vmcnt: sv/stv/trip-input writes complete
  if (tid == 0) {
    float x0 = 0.f, x1 = 0.f, x2 = 0.f;
    for (int k = 0; k < EPB; ++k) { x0 += s_t3[0][k]; x1 += s_t3[1][k]; x2 += s_t3[2][k]; }
    trip[bid * 4 + 0] = x0; trip[bid * 4 + 1] = x1; trip[bid * 4 + 2] = x2;
    __threadfence();                               // release
    const unsigned old = atomicAdd(ctr, 1u);
    s_last = (old == (unsigned)(nblk - 1)) ? 1 : 0;
  }
  __syncthreads();
  if (!s_last) return;
  __threadfence();                                 // acquire
  __syncthreads();

  // ======== Tail: only the last-finishing block ========
  float* s_val = s_a;   // reuse (pred staging is dead)

  // Load sorted arrays; read per-block MSE partials
  for (int i = tid; i < N_MAX; i += TPB) {
    s_val[i] = (i < n) ? sv[i] : -3.0e38f;
    s_ts[i]  = (i < n) ? stv[i] : 0.f;
  }
  float a0 = 0.f, a1 = 0.f, a2 = 0.f, a3 = 0.f;
  if (tid < nblk) {
    const float4 tv = *(const float4*)&trip[tid * 4];
    a0 = tv.x; a1 = tv.y; a2 = tv.z;
  }
  block_reduce4(a0, a1, a2, a3, s_red, tid, TPB);  // barriers cover staging

  // ---- Chunk PAV (threads 0..NCHUNK-1), top-2 stack entries in registers ----
  if (tid < NCHUNK) {
    const int base = tid * CS;
    const int lim  = (n - base < CS) ? (n - base) : CS;
    int sp = 0;
    double t0s = 0.0, t1s = 0.0;
    int t0c = 0, t1c = 0, t0st = 0, t1st = 0;
    if (lim > 0) {
#pragma unroll
      for (int kb = 0; kb < CS; kb += 4) {
        const float4 v4 = *(const float4*)&s_val[base + kb];
        const float fa[4] = {v4.x, v4.y, v4.z, v4.w};
#pragma unroll
        for (int u = 0; u < 4; ++u) {
          if (kb + u < lim) {
            const int i = base + kb + u;
            double cs_ = (double)fa[u] - (double)(n - i);
            int cc = 1, cst = i;
            while (sp > 0 && t0s * (double)cc <= cs_ * (double)t0c) {
              cs_ += t0s; cc += t0c; cst = t0st;
              sp--;
              t0s = t1s; t0c = t1c; t0st = t1st;
              if (sp >= 2) { t1s = st_sum[base + sp - 2]; t1c = st_cnt[base + sp - 2]; t1st = st_start[base + sp - 2]; }
            }
            if (sp >= 2) { st_sum[base + sp - 2] = t1s; st_cnt[base + sp - 2] = t1c; st_start[base + sp - 2] = t1st; }
            t1s = t0s; t1c = t0c; t1st = t0st;
            t0s = cs_; t0c = cc; t0st = cst;
            sp++;
          }
        }
      }
      // flush top-2 to LDS (canonical layout for the merge)
      if (sp >= 1) { st_sum[base + sp - 1] = t0s; st_cnt[base + sp - 1] = t0c; st_start[base + sp - 1] = t0st; }
      if (sp >= 2) { st_sum[base + sp - 2] = t1s; st_cnt[base + sp - 2] = t1c; st_start[base + sp - 2] = t1st; }
    }
    s_nb[tid] = (lim > 0) ? sp : 0;
  }
  __syncthreads();

  // Inclusive scan of s_nb (128 entries: 2 waves + carry)
  if (tid < NCHUNK) {
    int v = s_nb[tid];
#pragma unroll
    for (int d = 1; d < 64; d <<= 1) {
      const int u = __shfl_up(v, d, 64);
      if ((tid & 63) >= d) v += u;
    }
    s_scan[tid] = v;
  }
  __syncthreads();
  if (tid >= 64 && tid < NCHUNK) s_scan[tid] += s_scan[63];
  __syncthreads();

  // ---- Merge (wave 0): shuffle-fed serial pooling, top-2 in registers ----
  if (tid < 64) {
    const int B = s_scan[NCHUNK - 1];
    double t0s = 0.0, t1s = 0.0;
    int t0c = 0, t1c = 0, t0st = 0, t1st = 0;
    int gp = 0;
    for (int basb = 0; basb < B; basb += 64) {
      double lsum = 0.0; int lcnt = 1, lstart = 0;
      const int g = basb + tid;
      if (g < B) {
        int lo = 0, hi = NCHUNK - 1;
        while (lo < hi) { const int mid = (lo + hi) >> 1; if (s_scan[mid] > g) hi = mid; else lo = mid + 1; }
        const int k = g - (s_scan[lo] - s_nb[lo]);
        const int a = lo * CS + k;
        lsum = st_sum[a]; lcnt = st_cnt[a]; lstart = st_start[a];
      }
      const int lim = (B - basb < 64) ? (B - basb) : 64;
      for (int r = 0; r < lim; ++r) {
        double cs_ = __shfl(lsum, r, 64);
        int cc  = __shfl(lcnt, r, 64);
        int cst = __shfl(lstart, r, 64);
        while (gp > 0 && t0s * (double)cc <= cs_ * (double)t0c) {
          cs_ += t0s; cc += t0c; cst = t0st;
          gp--;
          t0s = t1s; t0c = t1c; t0st = t1st;
          if (gp >= 2) { t1s = st_sum[gp - 2]; t1c = st_cnt[gp - 2]; t1st = st_start[gp - 2]; }
        }
        if (gp >= 2 && tid == 0) { st_sum[gp - 2] = t1s; st_cnt[gp - 2] = t1c; st_start[gp - 2] = t1st; }
        t1s = t0s; t1c = t0c; t1st = t0st;
        t0s = cs_; t0c = cc; t0st = cst;
        gp++;
      }
    }
    if (tid == 0) {
      if (gp >= 1) { st_sum[gp - 1] = t0s; st_cnt[gp - 1] = t0c; st_start[gp - 1] = t0st; }
      if (gp >= 2) { st_sum[gp - 2] = t1s; st_cnt[gp - 2] = t1c; st_start[gp - 2] = t1st; }
      s_sp = gp;
    }
  }
  __syncthreads();

  // q[b] = block mean + C
  const int sp = s_sp;
  const double Cd = 0.5 * (double)(n + 1);
  for (int b = tid; b < sp; b += TPB)
    s_q[b] = (float)(st_sum[b] / (double)st_cnt[b] + Cd);
  __syncthreads();

  // ---- Phase B: sorted-order sums of centered ranks ----
  float b0 = 0.f, b1 = 0.f, b2 = 0.f, b3 = 0.f;
  for (int i = tid; i < n; i += TPB) {
    int lo = 0, hi = sp - 1;
    while (lo < hi) { const int mid = (lo + hi + 1) >> 1; if (st_start[mid] <= i) lo = mid; else hi = mid - 1; }
    const float rc = s_val[i] - s_q[lo];
    const float tt = s_ts[i];
    b0 += rc; b1 += rc * rc; b2 += rc * tt;
  }
  block_reduce4(b0, b1, b2, b3, s_red, tid, TPB);

  if (tid == 0) {
    const double nn = (double)n;
    const double cov = (double)b2 - (double)b0 * (double)a1 / nn;
    const double vr  = (double)b1 - (double)b0 * (double)b0 / nn;
    const double vt  = (double)a2 - (double)a1 * (double)a1 / nn;
    out[0] = (float)(-0.1 * cov / sqrt(vr * vt) + (double)a0 / nn);
  }
}

// ---- Fallback (R2-validated monolithic kernel) if ws is too small ----
__global__ __launch_bounds__(NTHR_M, 1)
void spearman_mono(const float* __restrict__ pred,
                   const float* __restrict__ target,
                   float* __restrict__ out, int n) {
  __shared__ float  s_val[N_MAX];
  __shared__ int    s_idx[N_MAX];
  __shared__ float  s_tp[N_MAX];
  __shared__ float  s_q[N_MAX];
  __shared__ double st_sum[N_MAX];
  __shared__ int    st_cnt[N_MAX];
  __shared__ int    st_start[N_MAX];
  __shared__ int    s_nb[NCHUNK];
  __shared__ int    s_sp;
  __shared__ float  s_red[64];

  const int tid = threadIdx.x;
  float a0 = 0.f, a1 = 0.f, a2 = 0.f;
  for (int i = tid; i < N_MAX; i += NTHR_M) {
    float p, t;
    if (i < n) { p = pred[i]; t = target[i]; }
    else       { p = -3.0e38f; t = 0.f; }
    s_val[i] = p; s_idx[i] = i; s_tp[i] = t;
    if (i < n) { const float d = p - t; a0 += d * d; a1 += t; a2 += t * t; }
  }
  float a3 = 0.f;
  block_reduce4(a0, a1, a2, a3, s_red, tid, NTHR_M);

  for (int k = 2; k <= N_MAX; k <<= 1) {
    for (int j = k >> 1; j >= 1; j >>= 1) {
      __syncthreads();
#pragma unroll 2
      for (int t = tid; t < N_MAX / 2; t += NTHR_M) {
        const int l = t & (j - 1);
        const int i = ((t ^ l) << 1) | l;
        const int p = i | j;
        const bool up = ((i & k) == 0);
        const float a = s_val[i], b = s_val[p];
        if ((a < b) == up) {
          s_val[i] = b; s_val[p] = a;
          const int ia = s_idx[i]; s_idx[i] = s_idx[p]; s_idx[p] = ia;
        }
      }
    }
  }
  __syncthreads();

  if (tid < NCHUNK) {
    const int base = tid * CS;
    const int lim  = (n - base < CS) ? (n - base) : CS;
    int sp = 0; double tsum = 0.0; int tcnt = 0, tstart = 0;
    for (int k = 0; k < lim; ++k) {
      const int i = base + k;
      double cs_ = (double)s_val[i] - (double)(n - i);
      int cc = 1, cst = i;
      while (sp > 0 && tsum * (double)cc <= cs_ * (double)tcnt) {
        cs_ += tsum; cc += tcnt; cst = tstart; sp--;
        if (sp > 0) {
          tsum = st_sum[base + sp - 1]; tcnt = st_cnt[base + sp - 1];
          tstart = st_start[base + sp - 1];
        }
      }
      if (sp > 0) {
        st_sum[base + sp - 1] = tsum; st_cnt[base + sp - 1] = tcnt;
        st_start[base + sp - 1] = tstart;
      }
      tsum = cs_; tcnt = cc; tstart = cst; sp++;
    }
    if (lim > 0) {
      st_sum[base + sp - 1] = tsum; st_cnt[base + sp - 1] = tcnt;
      st_start[base + sp - 1] = tstart; s_nb[tid] = sp;
    } else s_nb[tid] = 0;
  }
  __syncthreads();

  if (tid == 0) {
    int gp = 0; double tsum = 0.0; int tcnt = 0, tstart = 0;
    for (int c = 0; c < NCHUNK; ++c) {
      const int nb = s_nb[c], rb = c * CS;
      for (int k = 0; k < nb; ++k) {
        double cs_ = st_sum[rb + k];
        int cc = st_cnt[rb + k], cst = st_start[rb + k];
        while (gp > 0 && tsum * (double)cc <= cs_ * (double)tcnt) {
          cs_ += tsum; cc += tcnt; cst = tstart; gp--;
          if (gp > 0) {
            tsum = st_sum[gp - 1]; tcnt = st_cnt[gp - 1]; tstart = st_start[gp - 1];
          }
        }
        if (gp > 0) {
          st_sum[gp - 1] = tsum; st_cnt[gp - 1] = tcnt; st_start[gp - 1] = tstart;
        }
        tsum = cs_; tcnt = cc; tstart = cst; gp++;
      }
    }
    if (gp > 0) { st_sum[gp - 1] = tsum; st_cnt[gp - 1] = tcnt; st_start[gp - 1] = tstart; }
    s_sp = gp;
    const double Cd2 = 0.5 * (double)(n + 1);
    for (int b = 0; b < gp; ++b)
      s_q[b] = (float)(st_sum[b] / (double)st_cnt[b] + Cd2);
  }
  __syncthreads();

  const int sp = s_sp;
  float b0 = 0.f, b1 = 0.f, b2 = 0.f, b3 = 0.f;
  for (int i = tid; i < n; i += NTHR_M) {
    int lo = 0, hi = sp - 1;
    while (lo < hi) {
      const int mid = (lo + hi + 1) >> 1;
      if (st_start[mid] <= i) lo = mid; else hi = mid - 1;
    }
    const float rc = s_val[i] - s_q[lo];
    const float t  = s_tp[s_idx[i]];
    b0 += rc; b1 += rc * rc; b2 += rc * t;
  }
  block_reduce4(b0, b1, b2, b3, s_red, tid, NTHR_M);

  if (tid == 0) {
    const double nn = (double)n;
    const double cov = (double)b2 - (double)b0 * (double)a1 / nn;
    const double vr  = (double)b1 - (double)b0 * (double)b0 / nn;
    const double vt  = (double)a2 - (double)a1 * (double)a1 / nn;
    out[0] = (float)(-0.1 * cov / sqrt(vr * vt) + (double)a0 / nn);
  }
}

extern "C" void kernel_launch(void* const* d_in, const int* in_sizes, int n_in,
                              void* d_out, int out_size, void* d_ws, size_t ws_size,
                              hipStream_t stream) {
  const float* pred   = (const float*)d_in[0];
  const float* target = (const float*)d_in[1];
  float* out = (float*)d_out;
  const int n = in_sizes[0];
  const int nblk = (n + EPB - 1) / EPB;

  // ws layout (floats): [0..3] counter+pad | [4..1027] trip | [1028..5123] sv | [5124..9219] stv
  const size_t need = (size_t)(4 + 4 * TPB + 2 * N_MAX) * sizeof(float);
  if (ws_size >= need && n <= N_MAX && nblk <= TPB) {
    float* W = (float*)d_ws;
    hipMemsetAsync(d_ws, 0, 16, stream);   // zero the arrival counter each launch
    fused_kernel<<<nblk, TPB, 0, stream>>>(
        pred, target, out,
        (unsigned*)W, W + 4, W + 4 + 4 * TPB, W + 4 + 4 * TPB + N_MAX,
        n, nblk);
  } else {
    spearman_mono<<<1, NTHR_M, 0, stream>>>(pred, target, out, n);
  }
}

// Round 5
// 16.315 us; speedup vs baseline: 4.3863x; 4.3863x over previous
//
#include <hip/hip_runtime.h>
#include <math.h>

#define N_MAX 4096
#define NTHR  1024
#define CS    32
#define NCHUNK (N_MAX / CS)   // 128

// Reduce 4 float sums across the block. scr >= 64 floats.
__device__ inline void block_reduce4(float& x, float& y, float& z, float& w,
                                     volatile float* scr, int tid) {
#pragma unroll
  for (int o = 32; o > 0; o >>= 1) {
    x += __shfl_down(x, o, 64);
    y += __shfl_down(y, o, 64);
    z += __shfl_down(z, o, 64);
    w += __shfl_down(w, o, 64);
  }
  const int wv = tid >> 6, ln = tid & 63;
  __syncthreads();
  if (ln == 0) { scr[wv] = x; scr[16 + wv] = y; scr[32 + wv] = z; scr[48 + wv] = w; }
  __syncthreads();
  if (tid == 0) {
    float sx = 0.f, sy = 0.f, sz = 0.f, sw = 0.f;
    for (int k = 0; k < 16; ++k) {
      sx += scr[k]; sy += scr[16 + k]; sz += scr[32 + k]; sw += scr[48 + k];
    }
    scr[0] = sx; scr[16] = sy; scr[32] = sz; scr[48] = sw;
  }
  __syncthreads();
  x = scr[0]; y = scr[16]; z = scr[32]; w = scr[48];
}

// 6 sums + min + max across the block. scr >= 128 floats.
__device__ inline void block_reduce8(float* s, float& mn, float& mx,
                                     volatile float* scr, int tid) {
#pragma unroll
  for (int o = 32; o > 0; o >>= 1) {
#pragma unroll
    for (int q = 0; q < 6; ++q) s[q] += __shfl_down(s[q], o, 64);
    mn = fminf(mn, __shfl_down(mn, o, 64));
    mx = fmaxf(mx, __shfl_down(mx, o, 64));
  }
  const int wv = tid >> 6, ln = tid & 63;
  __syncthreads();
  if (ln == 0) {
#pragma unroll
    for (int q = 0; q < 6; ++q) scr[q * 16 + wv] = s[q];
    scr[96 + wv] = mn; scr[112 + wv] = mx;
  }
  __syncthreads();
  if (tid == 0) {
#pragma unroll
    for (int q = 0; q < 6; ++q) {
      float acc = scr[q * 16];
      for (int k = 1; k < 16; ++k) acc += scr[q * 16 + k];
      scr[q * 16] = acc;
    }
    float amn = scr[96], amx = scr[112];
    for (int k = 1; k < 16; ++k) {
      amn = fminf(amn, scr[96 + k]); amx = fmaxf(amx, scr[112 + k]);
    }
    scr[96] = amn; scr[112] = amx;
  }
  __syncthreads();
#pragma unroll
  for (int q = 0; q < 6; ++q) s[q] = scr[q * 16];
  mn = scr[96]; mx = scr[112];
}

__global__ __launch_bounds__(NTHR, 1)
void spearman_one(const float* __restrict__ pred,
                  const float* __restrict__ target,
                  float* __restrict__ out, int n) {
  // LDS superset: fast path uses s_red + s_bins; fallback uses the rest.
  __shared__ float  s_val[N_MAX];
  __shared__ int    s_idx[N_MAX];
  __shared__ float  s_tp[N_MAX];
  __shared__ float  s_q[N_MAX];
  __shared__ double st_sum[N_MAX];
  __shared__ int    st_cnt[N_MAX];
  __shared__ int    st_start[N_MAX];
  __shared__ int    s_nb[NCHUNK];
  __shared__ int    s_sp;
  __shared__ float  s_red[128];
  __shared__ int    s_bins[64];
  __shared__ int    s_safe;

  const int tid = threadIdx.x;

  // ---- Load 4 contiguous elements per thread into registers ----
  float p[4], t[4];
  const int base = tid * 4;
  int cntv = 0;
  if (base + 3 < n) {
    const float4 p4 = *(const float4*)&pred[base];
    const float4 t4 = *(const float4*)&target[base];
    p[0] = p4.x; p[1] = p4.y; p[2] = p4.z; p[3] = p4.w;
    t[0] = t4.x; t[1] = t4.y; t[2] = t4.z; t[3] = t4.w;
    cntv = 4;
  } else {
#pragma unroll
    for (int u = 0; u < 4; ++u) {
      const int i = base + u;
      if (i < n) { p[u] = pred[i]; t[u] = target[i]; cntv = u + 1; }
      else       { p[u] = 0.f; t[u] = 0.f; }
    }
  }

  // ---- Partial sums: Sp, Spp, St, Stt, Spt, Sdd + min/max of p ----
  float s[6] = {0.f, 0.f, 0.f, 0.f, 0.f, 0.f};
  float mn = 3.0e38f, mx = -3.0e38f;
#pragma unroll
  for (int u = 0; u < 4; ++u) {
    if (u < cntv) {
      s[0] += p[u]; s[1] += p[u] * p[u];
      s[2] += t[u]; s[3] += t[u] * t[u];
      s[4] += p[u] * t[u];
      const float d = p[u] - t[u];
      s[5] += d * d;
      mn = fminf(mn, p[u]); mx = fmaxf(mx, p[u]);
    }
  }
  if (tid < 64) s_bins[tid] = 0;
  block_reduce8(s, mn, mx, s_red, tid);   // barriers also cover s_bins init

  // ---- Histogram of p with bin width 0.25 ----
#pragma unroll
  for (int u = 0; u < 4; ++u) {
    if (u < cntv) {
      int b = (int)floorf((p[u] - mn) * 4.0f);
      b = b < 0 ? 0 : (b > 63 ? 63 : b);
      atomicAdd(&s_bins[b], 1);
    }
  }
  __syncthreads();

  // ---- Gap check + closed form (thread 0) ----
  // All sorted-adjacent gaps < 1  =>  z = s - [n..1] strictly increasing
  // => non-increasing PAV pools totally => ranks = p - mean(p) + (n+1)/2
  // => loss = MSE - 0.1 * pearson(p, t).
  // A gap >= 1 forces >= 3 consecutive empty 0.25-wide bins => detected.
  if (tid == 0) {
    int safe = 1;
    const float range = mx - mn;
    if (!(range < 15.75f)) {
      safe = 0;                       // bins insufficient (or NaN)
    } else {
      int last = (int)floorf(range * 4.0f);
      if (last > 63) last = 63;
      int run = 0;
      for (int k = 0; k <= last; ++k) {
        run = (s_bins[k] == 0) ? run + 1 : 0;
        if (run >= 3) { safe = 0; break; }
      }
    }
    s_safe = safe;
    if (safe) {
      const double nn = (double)n;
      const double Sp = s[0], Spp = s[1], St = s[2], Stt = s[3],
                   Spt = s[4], Sdd = s[5];
      const double cov = Spt - Sp * St / nn;
      const double vp  = Spp - Sp * Sp / nn;
      const double vt  = Stt - St * St / nn;
      out[0] = (float)(-0.1 * cov / sqrt(vp * vt) + Sdd / nn);
    }
  }
  __syncthreads();
  if (s_safe) return;

  // ================= Fallback: exact bitonic + PAV (R2-validated) =========
  // a0 = Sdd, a1 = St, a2 = Stt already reduced (in s[5], s[2], s[3]).
#pragma unroll
  for (int u = 0; u < 4; ++u) {
    const int i = base + u;
    if (i < n) { s_val[i] = p[u]; s_tp[i] = t[u]; }
    else       { s_val[i] = -3.0e38f; s_tp[i] = 0.f; }
    s_idx[i] = i;
  }
  __syncthreads();

  for (int k = 2; k <= N_MAX; k <<= 1) {
    for (int j = k >> 1; j >= 1; j >>= 1) {
#pragma unroll 2
      for (int tq = tid; tq < N_MAX / 2; tq += NTHR) {
        const int l = tq & (j - 1);
        const int i = ((tq ^ l) << 1) | l;
        const int pp = i | j;
        const bool up = ((i & k) == 0);
        const float a = s_val[i], b = s_val[pp];
        if ((a < b) == up) {
          s_val[i] = b; s_val[pp] = a;
          const int ia = s_idx[i]; s_idx[i] = s_idx[pp]; s_idx[pp] = ia;
        }
      }
      __syncthreads();
    }
  }

  if (tid < NCHUNK) {
    const int cbase = tid * CS;
    const int lim  = (n - cbase < CS) ? (n - cbase) : CS;
    int sp = 0; double tsum = 0.0; int tcnt = 0, tstart = 0;
    for (int k = 0; k < lim; ++k) {
      const int i = cbase + k;
      double cs_ = (double)s_val[i] - (double)(n - i);
      int cc = 1, cst = i;
      while (sp > 0 && tsum * (double)cc <= cs_ * (double)tcnt) {
        cs_ += tsum; cc += tcnt; cst = tstart; sp--;
        if (sp > 0) {
          tsum = st_sum[cbase + sp - 1]; tcnt = st_cnt[cbase + sp - 1];
          tstart = st_start[cbase + sp - 1];
        }
      }
      if (sp > 0) {
        st_sum[cbase + sp - 1] = tsum; st_cnt[cbase + sp - 1] = tcnt;
        st_start[cbase + sp - 1] = tstart;
      }
      tsum = cs_; tcnt = cc; tstart = cst; sp++;
    }
    if (lim > 0) {
      st_sum[cbase + sp - 1] = tsum; st_cnt[cbase + sp - 1] = tcnt;
      st_start[cbase + sp - 1] = tstart; s_nb[tid] = sp;
    } else s_nb[tid] = 0;
  }
  __syncthreads();

  if (tid == 0) {
    int gp = 0; double tsum = 0.0; int tcnt = 0, tstart = 0;
    for (int c = 0; c < NCHUNK; ++c) {
      const int nb = s_nb[c], rb = c * CS;
      for (int k = 0; k < nb; ++k) {
        double cs_ = st_sum[rb + k];
        int cc = st_cnt[rb + k], cst = st_start[rb + k];
        while (gp > 0 && tsum * (double)cc <= cs_ * (double)tcnt) {
          cs_ += tsum; cc += tcnt; cst = tstart; gp--;
          if (gp > 0) {
            tsum = st_sum[gp - 1]; tcnt = st_cnt[gp - 1]; tstart = st_start[gp - 1];
          }
        }
        if (gp > 0) {
          st_sum[gp - 1] = tsum; st_cnt[gp - 1] = tcnt; st_start[gp - 1] = tstart;
        }
        tsum = cs_; tcnt = cc; tstart = cst; gp++;
      }
    }
    if (gp > 0) { st_sum[gp - 1] = tsum; st_cnt[gp - 1] = tcnt; st_start[gp - 1] = tstart; }
    s_sp = gp;
    const double Cd = 0.5 * (double)(n + 1);
    for (int b = 0; b < gp; ++b)
      s_q[b] = (float)(st_sum[b] / (double)st_cnt[b] + Cd);
  }
  __syncthreads();

  const int sp = s_sp;
  float b0 = 0.f, b1 = 0.f, b2 = 0.f, b3 = 0.f;
  for (int i = tid; i < n; i += NTHR) {
    int lo = 0, hi = sp - 1;
    while (lo < hi) {
      const int mid = (lo + hi + 1) >> 1;
      if (st_start[mid] <= i) lo = mid; else hi = mid - 1;
    }
    const float rc = s_val[i] - s_q[lo];
    const float tt = s_tp[s_idx[i]];
    b0 += rc; b1 += rc * rc; b2 += rc * tt;
  }
  block_reduce4(b0, b1, b2, b3, s_red, tid);

  if (tid == 0) {
    const double nn = (double)n;
    const double cov = (double)b2 - (double)b0 * (double)s[2] / nn;
    const double vr  = (double)b1 - (double)b0 * (double)b0 / nn;
    const double vt  = (double)s[3] - (double)s[2] * (double)s[2] / nn;
    out[0] = (float)(-0.1 * cov / sqrt(vr * vt) + (double)s[5] / nn);
  }
}

extern "C" void kernel_launch(void* const* d_in, const int* in_sizes, int n_in,
                              void* d_out, int out_size, void* d_ws, size_t ws_size,
                              hipStream_t stream) {
  const float* pred   = (const float*)d_in[0];
  const float* target = (const float*)d_in[1];
  float* out = (float*)d_out;
  const int n = in_sizes[0];
  spearman_one<<<1, NTHR, 0, stream>>>(pred, target, out, n);
}

// Round 6
// 12.367 us; speedup vs baseline: 5.7869x; 1.3193x over previous
//
#include <hip/hip_runtime.h>
#include <math.h>

#define N_MAX 4096
#define NTHR  512
#define EPT   8                 // elements per thread
#define CS    32
#define NCHUNK (N_MAX / CS)     // 128

// Reduce 4 float sums across the block (NTHR threads). scr >= 64 floats.
__device__ inline void block_reduce4(float& x, float& y, float& z, float& w,
                                     volatile float* scr, int tid) {
#pragma unroll
  for (int o = 32; o > 0; o >>= 1) {
    x += __shfl_down(x, o, 64);
    y += __shfl_down(y, o, 64);
    z += __shfl_down(z, o, 64);
    w += __shfl_down(w, o, 64);
  }
  const int wv = tid >> 6, ln = tid & 63;
  __syncthreads();
  if (ln == 0) { scr[wv] = x; scr[16 + wv] = y; scr[32 + wv] = z; scr[48 + wv] = w; }
  __syncthreads();
  if (tid == 0) {
    float sx = 0.f, sy = 0.f, sz = 0.f, sw = 0.f;
    for (int k = 0; k < NTHR / 64; ++k) {
      sx += scr[k]; sy += scr[16 + k]; sz += scr[32 + k]; sw += scr[48 + k];
    }
    scr[0] = sx; scr[16] = sy; scr[32] = sz; scr[48] = sw;
  }
  __syncthreads();
  x = scr[0]; y = scr[16]; z = scr[32]; w = scr[48];
}

__global__ __launch_bounds__(NTHR, 1)
void spearman_one(const float* __restrict__ pred,
                  const float* __restrict__ target,
                  float* __restrict__ out, int n) {
  // Fallback storage (fast path touches only the small arrays at the end).
  __shared__ float  s_val[N_MAX];
  __shared__ int    s_idx[N_MAX];
  __shared__ float  s_tp[N_MAX];
  __shared__ float  s_q[N_MAX];
  __shared__ double st_sum[N_MAX];
  __shared__ int    st_cnt[N_MAX];
  __shared__ int    st_start[N_MAX];
  __shared__ int    s_nb[NCHUNK];
  __shared__ int    s_sp;
  __shared__ float  s_red[64];
  __shared__ float  s_part[6 * 8];   // per-wave partials (6 sums x 8 waves)
  __shared__ float  s_sums[6];       // block totals (thread 0)
  __shared__ int    s_bins[64];
  __shared__ int    s_flag;          // out-of-window flag
  __shared__ int    s_minb, s_maxb;
  __shared__ int    s_safe;

  const int tid = threadIdx.x;
  const int wv = tid >> 6, ln = tid & 63;

  // ---- Load EPT contiguous elements per thread into registers ----
  float p[EPT], t[EPT];
  const int base = tid * EPT;
  int cntv = 0;
  if (base + EPT - 1 < n) {
    const float4 pa = *(const float4*)&pred[base];
    const float4 pb = *(const float4*)&pred[base + 4];
    const float4 ta = *(const float4*)&target[base];
    const float4 tb = *(const float4*)&target[base + 4];
    p[0]=pa.x; p[1]=pa.y; p[2]=pa.z; p[3]=pa.w; p[4]=pb.x; p[5]=pb.y; p[6]=pb.z; p[7]=pb.w;
    t[0]=ta.x; t[1]=ta.y; t[2]=ta.z; t[3]=ta.w; t[4]=tb.x; t[5]=tb.y; t[6]=tb.z; t[7]=tb.w;
    cntv = EPT;
  } else {
#pragma unroll
    for (int u = 0; u < EPT; ++u) {
      const int i = base + u;
      if (i < n) { p[u] = pred[i]; t[u] = target[i]; cntv = u + 1; }
      else       { p[u] = 0.f; t[u] = 0.f; }
    }
  }
  const float anchor = pred[0];        // uniform (scalar) load

  // ---- Init bins/flags, then barrier ----
  if (tid < 64) s_bins[tid] = 0;
  if (tid == 0) { s_flag = 0; s_minb = 64; s_maxb = -1; }
  __syncthreads();                                    // barrier 1

  // ---- Histogram (bin width 0.25, 64 bins anchored at pred[0]-8) +
  //      per-thread partial sums, all in one pass ----
  float s0=0.f,s1=0.f,s2=0.f,s3=0.f,s4=0.f,s5=0.f;
  int lminb = 64, lmaxb = -1, oow = 0;
#pragma unroll
  for (int u = 0; u < EPT; ++u) {
    if (u < cntv) {
      s0 += p[u]; s1 += p[u]*p[u];
      s2 += t[u]; s3 += t[u]*t[u];
      s4 += p[u]*t[u];
      const float d = p[u] - t[u];
      s5 += d*d;
      const int b = (int)floorf((p[u] - anchor) * 4.0f) + 32;
      if (b < 0 || b > 63) oow = 1;
      else {
        atomicAdd(&s_bins[b], 1);
        lminb = b < lminb ? b : lminb;
        lmaxb = b > lmaxb ? b : lmaxb;
      }
    }
  }
  if (oow) atomicOr(&s_flag, 1);
  if (lmaxb >= 0) { atomicMin(&s_minb, lminb); atomicMax(&s_maxb, lmaxb); }

  // wave-level reduce of the 6 sums; lane 0 writes partials
#pragma unroll
  for (int o = 32; o > 0; o >>= 1) {
    s0 += __shfl_down(s0, o, 64); s1 += __shfl_down(s1, o, 64);
    s2 += __shfl_down(s2, o, 64); s3 += __shfl_down(s3, o, 64);
    s4 += __shfl_down(s4, o, 64); s5 += __shfl_down(s5, o, 64);
  }
  if (ln == 0) {
    s_part[0*8+wv]=s0; s_part[1*8+wv]=s1; s_part[2*8+wv]=s2;
    s_part[3*8+wv]=s3; s_part[4*8+wv]=s4; s_part[5*8+wv]=s5;
  }
  __syncthreads();                                    // barrier 2

  // ---- Wave 0: ballot gap check; thread 0: combine + closed form ----
  unsigned long long mask = 0;
  if (tid < 64) mask = __ballot(s_bins[tid] == 0);
  if (tid == 0) {
    float S[6];
#pragma unroll
    for (int q = 0; q < 6; ++q) {
      float acc = s_part[q*8];
#pragma unroll
      for (int k = 1; k < 8; ++k) acc += s_part[q*8+k];
      S[q] = acc; s_sums[q] = acc;
    }
    int safe = (s_flag == 0) && (s_maxb >= s_minb);
    if (safe) {
      const int span = s_maxb - s_minb;
      const unsigned long long R =
          (span >= 63) ? ~0ull : (((1ull << (span + 1)) - 1ull) << s_minb);
      const unsigned long long em = mask & R;
      if (em & (em >> 1) & (em >> 2)) safe = 0;  // 3 consecutive empty bins
    }
    s_safe = safe;
    if (safe) {
      // All sorted gaps < 1  =>  z = s - [n..1] strictly increasing  =>
      // PAV pools totally  =>  loss = MSE - 0.1 * pearson(pred, target).
      const double nn = (double)n;
      const double Sp = S[0], Spp = S[1], St = S[2], Stt = S[3],
                   Spt = S[4], Sdd = S[5];
      const double cov = Spt - Sp * St / nn;
      const double vp  = Spp - Sp * Sp / nn;
      const double vt  = Stt - St * St / nn;
      out[0] = (float)(-0.1 * cov / sqrt(vp * vt) + Sdd / nn);
    }
  }
  __syncthreads();                                    // barrier 3
  if (s_safe) return;

  // ================= Fallback: exact bitonic + PAV (validated path) =======
#pragma unroll
  for (int u = 0; u < EPT; ++u) {
    const int i = base + u;
    if (i < n) { s_val[i] = p[u]; s_tp[i] = t[u]; }
    else       { s_val[i] = -3.0e38f; s_tp[i] = 0.f; }
    s_idx[i] = i;
  }
  __syncthreads();

  for (int k = 2; k <= N_MAX; k <<= 1) {
    for (int j = k >> 1; j >= 1; j >>= 1) {
#pragma unroll 2
      for (int tq = tid; tq < N_MAX / 2; tq += NTHR) {
        const int l = tq & (j - 1);
        const int i = ((tq ^ l) << 1) | l;
        const int pp = i | j;
        const bool up = ((i & k) == 0);
        const float a = s_val[i], b = s_val[pp];
        if ((a < b) == up) {
          s_val[i] = b; s_val[pp] = a;
          const int ia = s_idx[i]; s_idx[i] = s_idx[pp]; s_idx[pp] = ia;
        }
      }
      __syncthreads();
    }
  }

  if (tid < NCHUNK) {
    const int cbase = tid * CS;
    const int lim  = (n - cbase < CS) ? (n - cbase) : CS;
    int sp = 0; double tsum = 0.0; int tcnt = 0, tstart = 0;
    for (int k = 0; k < lim; ++k) {
      const int i = cbase + k;
      double cs_ = (double)s_val[i] - (double)(n - i);
      int cc = 1, cst = i;
      while (sp > 0 && tsum * (double)cc <= cs_ * (double)tcnt) {
        cs_ += tsum; cc += tcnt; cst = tstart; sp--;
        if (sp > 0) {
          tsum = st_sum[cbase + sp - 1]; tcnt = st_cnt[cbase + sp - 1];
          tstart = st_start[cbase + sp - 1];
        }
      }
      if (sp > 0) {
        st_sum[cbase + sp - 1] = tsum; st_cnt[cbase + sp - 1] = tcnt;
        st_start[cbase + sp - 1] = tstart;
      }
      tsum = cs_; tcnt = cc; tstart = cst; sp++;
    }
    if (lim > 0) {
      st_sum[cbase + sp - 1] = tsum; st_cnt[cbase + sp - 1] = tcnt;
      st_start[cbase + sp - 1] = tstart; s_nb[tid] = sp;
    } else s_nb[tid] = 0;
  }
  __syncthreads();

  if (tid == 0) {
    int gp = 0; double tsum = 0.0; int tcnt = 0, tstart = 0;
    for (int c = 0; c < NCHUNK; ++c) {
      const int nb = s_nb[c], rb = c * CS;
      for (int k = 0; k < nb; ++k) {
        double cs_ = st_sum[rb + k];
        int cc = st_cnt[rb + k], cst = st_start[rb + k];
        while (gp > 0 && tsum * (double)cc <= cs_ * (double)tcnt) {
          cs_ += tsum; cc += tcnt; cst = tstart; gp--;
          if (gp > 0) {
            tsum = st_sum[gp - 1]; tcnt = st_cnt[gp - 1]; tstart = st_start[gp - 1];
          }
        }
        if (gp > 0) {
          st_sum[gp - 1] = tsum; st_cnt[gp - 1] = tcnt; st_start[gp - 1] = tstart;
        }
        tsum = cs_; tcnt = cc; tstart = cst; gp++;
      }
    }
    if (gp > 0) { st_sum[gp - 1] = tsum; st_cnt[gp - 1] = tcnt; st_start[gp - 1] = tstart; }
    s_sp = gp;
    const double Cd = 0.5 * (double)(n + 1);
    for (int b = 0; b < gp; ++b)
      s_q[b] = (float)(st_sum[b] / (double)st_cnt[b] + Cd);
  }
  __syncthreads();

  const int sp = s_sp;
  float b0 = 0.f, b1 = 0.f, b2 = 0.f, b3 = 0.f;
  for (int i = tid; i < n; i += NTHR) {
    int lo = 0, hi = sp - 1;
    while (lo < hi) {
      const int mid = (lo + hi + 1) >> 1;
      if (st_start[mid] <= i) lo = mid; else hi = mid - 1;
    }
    const float rc = s_val[i] - s_q[lo];
    const float tt = s_tp[s_idx[i]];
    b0 += rc; b1 += rc * rc; b2 += rc * tt;
  }
  block_reduce4(b0, b1, b2, b3, s_red, tid);

  if (tid == 0) {
    const double nn = (double)n;
    const double St = s_sums[2], Stt = s_sums[3], Sdd = s_sums[5];
    const double cov = (double)b2 - (double)b0 * St / nn;
    const double vr  = (double)b1 - (double)b0 * (double)b0 / nn;
    const double vt  = Stt - St * St / nn;
    out[0] = (float)(-0.1 * cov / sqrt(vr * vt) + Sdd / nn);
  }
}

extern "C" void kernel_launch(void* const* d_in, const int* in_sizes, int n_in,
                              void* d_out, int out_size, void* d_ws, size_t ws_size,
                              hipStream_t stream) {
  const float* pred   = (const float*)d_in[0];
  const float* target = (const float*)d_in[1];
  float* out = (float*)d_out;
  const int n = in_sizes[0];
  spearman_one<<<1, NTHR, 0, stream>>>(pred, target, out, n);
}

// Round 7
// 9.347 us; speedup vs baseline: 7.6564x; 1.3231x over previous
//
#include <hip/hip_runtime.h>
#include <math.h>

#define N_MAX 4096
#define NTHR  256
#define EPT   16                // elements per thread
#define CS    32
#define NCHUNK (N_MAX / CS)     // 128

// Reduce 4 float sums across the block (NTHR threads). scr >= 64 floats.
__device__ inline void block_reduce4(float& x, float& y, float& z, float& w,
                                     volatile float* scr, int tid) {
#pragma unroll
  for (int o = 32; o > 0; o >>= 1) {
    x += __shfl_down(x, o, 64);
    y += __shfl_down(y, o, 64);
    z += __shfl_down(z, o, 64);
    w += __shfl_down(w, o, 64);
  }
  const int wv = tid >> 6, ln = tid & 63;
  __syncthreads();
  if (ln == 0) { scr[wv] = x; scr[16 + wv] = y; scr[32 + wv] = z; scr[48 + wv] = w; }
  __syncthreads();
  if (tid == 0) {
    float sx = 0.f, sy = 0.f, sz = 0.f, sw = 0.f;
    for (int k = 0; k < NTHR / 64; ++k) {
      sx += scr[k]; sy += scr[16 + k]; sz += scr[32 + k]; sw += scr[48 + k];
    }
    scr[0] = sx; scr[16] = sy; scr[32] = sz; scr[48] = sw;
  }
  __syncthreads();
  x = scr[0]; y = scr[16]; z = scr[32]; w = scr[48];
}

__global__ __launch_bounds__(NTHR, 1)
void spearman_one(const float* __restrict__ pred,
                  const float* __restrict__ target,
                  float* __restrict__ out, int n) {
  // Fallback storage (fast path touches only the small arrays).
  __shared__ float  s_val[N_MAX];
  __shared__ int    s_idx[N_MAX];
  __shared__ float  s_tp[N_MAX];
  __shared__ float  s_q[N_MAX];
  __shared__ double st_sum[N_MAX];
  __shared__ int    st_cnt[N_MAX];
  __shared__ int    st_start[N_MAX];
  __shared__ int    s_nb[NCHUNK];
  __shared__ int    s_sp;
  __shared__ float  s_red[64];
  __shared__ float  s_part[6 * 4];   // 6 sums x 4 waves
  __shared__ float  s_sums[6];       // block totals (for fallback epilogue)
  __shared__ int    s_bins[64];      // emptiness flags (benign races)
  __shared__ int    s_flag;          // out-of-window flag (benign race)

  const int tid = threadIdx.x;
  const int wv = tid >> 6, ln = tid & 63;

  // ---- Load EPT contiguous elements per thread into registers ----
  float p[EPT], t[EPT];
  const int base = tid * EPT;
  int cntv = 0;
  if (base + EPT - 1 < n) {
#pragma unroll
    for (int q = 0; q < EPT / 4; ++q) {
      const float4 pv = *(const float4*)&pred[base + q * 4];
      const float4 tv = *(const float4*)&target[base + q * 4];
      p[q*4+0]=pv.x; p[q*4+1]=pv.y; p[q*4+2]=pv.z; p[q*4+3]=pv.w;
      t[q*4+0]=tv.x; t[q*4+1]=tv.y; t[q*4+2]=tv.z; t[q*4+3]=tv.w;
    }
    cntv = EPT;
  } else {
#pragma unroll
    for (int u = 0; u < EPT; ++u) {
      const int i = base + u;
      if (i < n) { p[u] = pred[i]; t[u] = target[i]; cntv = u + 1; }
      else       { p[u] = 0.f; t[u] = 0.f; }
    }
  }
  const float anchor = pred[0];        // uniform scalar load, overlaps vectors

  // ---- Init emptiness flags, then barrier 1 ----
  if (tid < 64) s_bins[tid] = 0;
  if (tid == 64 || (NTHR <= 64 && tid == 0)) {}  // (no-op, keep shape)
  if (tid == 0) s_flag = 0;
  __syncthreads();                                    // barrier 1

  // ---- One pass: partial sums + emptiness marks (no atomics) ----
  float s0=0.f,s1=0.f,s2=0.f,s3=0.f,s4=0.f,s5=0.f;
  int oow = 0;
#pragma unroll
  for (int u = 0; u < EPT; ++u) {
    if (u < cntv) {
      s0 += p[u]; s1 += p[u]*p[u];
      s2 += t[u]; s3 += t[u]*t[u];
      s4 += p[u]*t[u];
      const float d = p[u] - t[u];
      s5 += d*d;
      const int b = (int)floorf((p[u] - anchor) * 4.0f) + 32;
      if (b < 0 || b > 63) oow = 1;
      else s_bins[b] = 1;              // benign race: all writers store 1
    }
  }
  if (oow) s_flag = 1;                 // benign race

  // wave-level reduce of the 6 sums; lane 0 writes partials
#pragma unroll
  for (int o = 32; o > 0; o >>= 1) {
    s0 += __shfl_down(s0, o, 64); s1 += __shfl_down(s1, o, 64);
    s2 += __shfl_down(s2, o, 64); s3 += __shfl_down(s3, o, 64);
    s4 += __shfl_down(s4, o, 64); s5 += __shfl_down(s5, o, 64);
  }
  if (ln == 0) {
    s_part[0*4+wv]=s0; s_part[1*4+wv]=s1; s_part[2*4+wv]=s2;
    s_part[3*4+wv]=s3; s_part[4*4+wv]=s4; s_part[5*4+wv]=s5;
  }
  __syncthreads();                                    // barrier 2

  // ---- Every wave independently derives `safe` from its own ballot ----
  // nonempty-bin mask; minb/maxb via ctz/clz; 3 consecutive empties in the
  // occupied span => a sorted gap might reach 1.0 => exact fallback.
  const unsigned long long nonempty = __ballot(s_bins[ln] != 0);
  int safe = (s_flag == 0) && (nonempty != 0ull);
  if (safe) {
    const int minb = __ffsll((long long)nonempty) - 1;
    const int maxb = 63 - __clzll((long long)nonempty);
    const int span = maxb - minb;
    const unsigned long long R =
        (span >= 63) ? ~0ull : (((1ull << (span + 1)) - 1ull) << minb);
    const unsigned long long em = (~nonempty) & R;
    if (em & (em >> 1) & (em >> 2)) safe = 0;
  }

  if (safe) {
    if (tid == 0) {
      // gaps < 1 => z = s - [n..1] strictly increasing => PAV pools totally
      // => loss = MSE - 0.1 * pearson(pred, target).
      float S[6];
#pragma unroll
      for (int q = 0; q < 6; ++q)
        S[q] = s_part[q*4+0] + s_part[q*4+1] + s_part[q*4+2] + s_part[q*4+3];
      const double nn = (double)n;
      const double Sp = S[0], Spp = S[1], St = S[2], Stt = S[3],
                   Spt = S[4], Sdd = S[5];
      const double cov = Spt - Sp * St / nn;
      const double vp  = Spp - Sp * Sp / nn;
      const double vt  = Stt - St * St / nn;
      out[0] = (float)(-0.1 * cov / sqrt(vp * vt) + Sdd / nn);
    }
    return;   // uniform: all threads computed identical `safe`
  }

  // ================= Fallback: exact bitonic + PAV (validated path) =======
  if (tid == 0) {
#pragma unroll
    for (int q = 0; q < 6; ++q)
      s_sums[q] = s_part[q*4+0] + s_part[q*4+1] + s_part[q*4+2] + s_part[q*4+3];
  }
#pragma unroll
  for (int u = 0; u < EPT; ++u) {
    const int i = base + u;
    if (i < n) { s_val[i] = p[u]; s_tp[i] = t[u]; }
    else       { s_val[i] = -3.0e38f; s_tp[i] = 0.f; }
    s_idx[i] = i;
  }
  __syncthreads();

  for (int k = 2; k <= N_MAX; k <<= 1) {
    for (int j = k >> 1; j >= 1; j >>= 1) {
#pragma unroll 2
      for (int tq = tid; tq < N_MAX / 2; tq += NTHR) {
        const int l = tq & (j - 1);
        const int i = ((tq ^ l) << 1) | l;
        const int pp = i | j;
        const bool up = ((i & k) == 0);
        const float a = s_val[i], b = s_val[pp];
        if ((a < b) == up) {
          s_val[i] = b; s_val[pp] = a;
          const int ia = s_idx[i]; s_idx[i] = s_idx[pp]; s_idx[pp] = ia;
        }
      }
      __syncthreads();
    }
  }

  if (tid < NCHUNK) {
    const int cbase = tid * CS;
    const int lim  = (n - cbase < CS) ? (n - cbase) : CS;
    int sp = 0; double tsum = 0.0; int tcnt = 0, tstart = 0;
    for (int k = 0; k < lim; ++k) {
      const int i = cbase + k;
      double cs_ = (double)s_val[i] - (double)(n - i);
      int cc = 1, cst = i;
      while (sp > 0 && tsum * (double)cc <= cs_ * (double)tcnt) {
        cs_ += tsum; cc += tcnt; cst = tstart; sp--;
        if (sp > 0) {
          tsum = st_sum[cbase + sp - 1]; tcnt = st_cnt[cbase + sp - 1];
          tstart = st_start[cbase + sp - 1];
        }
      }
      if (sp > 0) {
        st_sum[cbase + sp - 1] = tsum; st_cnt[cbase + sp - 1] = tcnt;
        st_start[cbase + sp - 1] = tstart;
      }
      tsum = cs_; tcnt = cc; tstart = cst; sp++;
    }
    if (lim > 0) {
      st_sum[cbase + sp - 1] = tsum; st_cnt[cbase + sp - 1] = tcnt;
      st_start[cbase + sp - 1] = tstart; s_nb[tid] = sp;
    } else s_nb[tid] = 0;
  }
  __syncthreads();

  if (tid == 0) {
    int gp = 0; double tsum = 0.0; int tcnt = 0, tstart = 0;
    for (int c = 0; c < NCHUNK; ++c) {
      const int nb = s_nb[c], rb = c * CS;
      for (int k = 0; k < nb; ++k) {
        double cs_ = st_sum[rb + k];
        int cc = st_cnt[rb + k], cst = st_start[rb + k];
        while (gp > 0 && tsum * (double)cc <= cs_ * (double)tcnt) {
          cs_ += tsum; cc += tcnt; cst = tstart; gp--;
          if (gp > 0) {
            tsum = st_sum[gp - 1]; tcnt = st_cnt[gp - 1]; tstart = st_start[gp - 1];
          }
        }
        if (gp > 0) {
          st_sum[gp - 1] = tsum; st_cnt[gp - 1] = tcnt; st_start[gp - 1] = tstart;
        }
        tsum = cs_; tcnt = cc; tstart = cst; gp++;
      }
    }
    if (gp > 0) { st_sum[gp - 1] = tsum; st_cnt[gp - 1] = tcnt; st_start[gp - 1] = tstart; }
    s_sp = gp;
    const double Cd = 0.5 * (double)(n + 1);
    for (int b = 0; b < gp; ++b)
      s_q[b] = (float)(st_sum[b] / (double)st_cnt[b] + Cd);
  }
  __syncthreads();

  const int sp = s_sp;
  float b0 = 0.f, b1 = 0.f, b2 = 0.f, b3 = 0.f;
  for (int i = tid; i < n; i += NTHR) {
    int lo = 0, hi = sp - 1;
    while (lo < hi) {
      const int mid = (lo + hi + 1) >> 1;
      if (st_start[mid] <= i) lo = mid; else hi = mid - 1;
    }
    const float rc = s_val[i] - s_q[lo];
    const float tt = s_tp[s_idx[i]];
    b0 += rc; b1 += rc * rc; b2 += rc * tt;
  }
  block_reduce4(b0, b1, b2, b3, s_red, tid);

  if (tid == 0) {
    const double nn = (double)n;
    const double St = s_sums[2], Stt = s_sums[3], Sdd = s_sums[5];
    const double cov = (double)b2 - (double)b0 * St / nn;
    const double vr  = (double)b1 - (double)b0 * (double)b0 / nn;
    const double vt  = Stt - St * St / nn;
    out[0] = (float)(-0.1 * cov / sqrt(vr * vt) + Sdd / nn);
  }
}

extern "C" void kernel_launch(void* const* d_in, const int* in_sizes, int n_in,
                              void* d_out, int out_size, void* d_ws, size_t ws_size,
                              hipStream_t stream) {
  const float* pred   = (const float*)d_in[0];
  const float* target = (const float*)d_in[1];
  float* out = (float*)d_out;
  const int n = in_sizes[0];
  spearman_one<<<1, NTHR, 0, stream>>>(pred, target, out, n);
}